// Round 6
// baseline (373.295 us; speedup 1.0000x reference)
//
#include <hip/hip_runtime.h>
#include <cstdint>
#include <cstddef>

typedef unsigned short u16;
typedef unsigned int u32;
typedef __bf16 bf16x8 __attribute__((ext_vector_type(8)));
typedef float f32x4 __attribute__((ext_vector_type(4)));

#define SL 2048            // sequence length
#define NCH 8192           // B(16) * BIDIR(2) * N_OUT(256)
#define SEGS 64
#define SEGLEN 32

// out buffer element offsets (f32 output)
#define OFF_C2S 16777216
#define OFF_C1F 33554432
#define OFF_C2F 33562624
#define OFF_DF  33570816

__device__ __forceinline__ float bf2f(u16 u) {
  union { u32 i; float f; } v; v.i = ((u32)u) << 16; return v.f;
}
__device__ __forceinline__ u16 f2bf(float f) {
  union { float f; u32 i; } v; v.f = f;
  u32 x = v.i;
  return (u16)((x + 0x7fffu + ((x >> 16) & 1u)) >> 16);
}

// -------------------------------------------------------------------------
// Repack weight_in (f32, 256 x 3072, col = dir*1536 + n*6 + k) into bf16
// Wt[plane][ch2][kk]  (5 x 512 x 256, K-major) for contiguous GEMM B loads.
__global__ __launch_bounds__(256) void repack_kernel(
    const float* __restrict__ W, u16* __restrict__ Wt) {
  int idx = blockIdx.x * 256 + threadIdx.x;   // < 5*512*256 = 655360
  int kk = idx & 255;
  int rest = idx >> 8;
  int ch2 = rest & 511;
  int p = rest >> 9;
  Wt[idx] = f2bf(W[(size_t)kk * 3072 + (ch2 >> 8) * 1536 + (ch2 & 255) * 6 + p]);
}

// -------------------------------------------------------------------------
// MFMA GEMM over one flipped-time chunk [t0c, t0c+CHT). Block: 64 rows x 128
// cols; blockIdx.y = column tile (0..3) -> dir = tile>=2. A rows read from
// mirrored original time for dir=1, so buf is dense in flipped time.
// x f32 -> bf16 during LDS staging. Epilogue: bias+sigmoid for planes 3,4;
// record x2 at (tf&31)==31 into X2B[seg][ch] (bf16).
__global__ __launch_bounds__(256) void gemm_kernel(
    const float* __restrict__ x, const u16* __restrict__ Wt,
    const float* __restrict__ bias, u16* __restrict__ buf,
    u16* __restrict__ X2B, int t0c, int CHT) {
  __shared__ __align__(16) u16 As[2048 * 8];   // 32 KB
  __shared__ __align__(16) u16 Bs[1024 * 8];   // 16 KB
  const int tid = threadIdx.x;
  const int lane = tid & 63;
  const int wave = tid >> 6;
  const int wr = wave >> 1, wc = wave & 1;
  const int l15 = lane & 15, l4 = lane >> 4;
  const int rt = blockIdx.x;          // row tile within chunk (64 rows)
  const int ch0 = blockIdx.y * 128;   // 0,128,256,384
  const int dir = ch0 >> 8;           // 0 or 1

  // stage A strip (64 rows x 256 k): chunk = kb*64 + m, 8 elems each
#pragma unroll
  for (int i = 0; i < 8; ++i) {
    int chunk = tid + i * 256;
    int kb = chunk >> 6, m = chunk & 63;
    int tf = t0c + rt * 4 + (m >> 4);
    int ot = dir ? (SL - 1 - tf) : tf;
    int row = ot * 16 + (m & 15);
    const float* src = x + (size_t)row * 256 + kb * 8;
    f32x4 a = *(const f32x4*)src;
    f32x4 b = *(const f32x4*)(src + 4);
    union { bf16x8 v; u16 s[8]; } h;
#pragma unroll
    for (int j = 0; j < 4; ++j) { h.s[j] = f2bf(a[j]); h.s[4 + j] = f2bf(b[j]); }
    *(bf16x8*)(As + (size_t)chunk * 8) = h.v;
  }

  const size_t pstride = (size_t)CHT * NCH;
  for (int p = 0; p < 5; ++p) {
    f32x4 acc[2][4];
#pragma unroll
    for (int i = 0; i < 2; ++i)
#pragma unroll
      for (int j = 0; j < 4; ++j) acc[i][j] = (f32x4){0.f, 0.f, 0.f, 0.f};

    for (int kt = 0; kt < 4; ++kt) {
      bf16x8 rg[4];
#pragma unroll
      for (int i = 0; i < 4; ++i) {
        int chunk = tid + i * 256;
        int kbl = chunk >> 7, c = chunk & 127;
        rg[i] = *(const bf16x8*)(
            Wt + ((size_t)(p * 512 + ch0 + c) * 256 + kt * 64 + kbl * 8));
      }
      __syncthreads();   // previous iteration's LDS reads complete
#pragma unroll
      for (int i = 0; i < 4; ++i) {
        int chunk = tid + i * 256;
        *(bf16x8*)(Bs + (size_t)chunk * 8) = rg[i];
      }
      __syncthreads();   // Bs (and As on first pass) visible
#pragma unroll
      for (int h = 0; h < 2; ++h) {
        bf16x8 af[2], bfr[4];
#pragma unroll
        for (int i = 0; i < 2; ++i) {
          int kb = kt * 8 + h * 4 + l4;
          int m = wr * 32 + i * 16 + l15;
          af[i] = *(const bf16x8*)(As + (size_t)(kb * 64 + m) * 8);
        }
#pragma unroll
        for (int j = 0; j < 4; ++j) {
          int kbl = h * 4 + l4;
          int c = wc * 64 + j * 16 + l15;
          bfr[j] = *(const bf16x8*)(Bs + (size_t)(kbl * 128 + c) * 8);
        }
#pragma unroll
        for (int i = 0; i < 2; ++i)
#pragma unroll
          for (int j = 0; j < 4; ++j)
            acc[i][j] = __builtin_amdgcn_mfma_f32_16x16x32_bf16(
                af[i], bfr[j], acc[i][j], 0, 0, 0);
      }
    }

    // epilogue
    u16* pl = buf + (size_t)p * pstride;
#pragma unroll
    for (int j = 0; j < 4; ++j) {
      int ch2 = ch0 + wc * 64 + j * 16 + l15;
      float bv = (p >= 3) ? bias[p * 512 + ch2] : 0.f;
#pragma unroll
      for (int i = 0; i < 2; ++i) {
#pragma unroll
        for (int r = 0; r < 4; ++r) {
          int row = wr * 32 + i * 16 + l4 * 4 + r;   // 0..63 local
          int tl = rt * 4 + (row >> 4);
          int b = row & 15;
          float v = acc[i][j][r];
          if (p >= 3) v = 1.f / (1.f + __expf(-(v + bv)));
          u16 hv = f2bf(v);
          int ch = b * 512 + ch2;
          pl[(size_t)tl * NCH + ch] = hv;
          if (p == 1) {
            int tf = t0c + tl;
            if ((tf & 31) == 31) X2B[(size_t)(tf >> 5) * NCH + ch] = hv;
          }
        }
      }
    }
  }
}

// -------------------------------------------------------------------------
// Pass A (per chunk): per (channel, segment) affine summary for both recurrences.
__global__ __launch_bounds__(256) void scanA_kernel(
    const u16* __restrict__ buf, const float* __restrict__ d_init,
    const u16* __restrict__ X2B,
    float* __restrict__ A1, float* __restrict__ B1,
    float* __restrict__ A2, float* __restrict__ B2, int c, int CHT) {
  int bid = blockIdx.x;               // CHT/32 * 32 blocks
  int sl = bid >> 5, chg = bid & 31;
  int ch = chg * 256 + threadIdx.x;
  int s = c * (CHT / 32) + sl;        // global segment
  size_t pstride = (size_t)CHT * NCH;
  const u16* p0 = buf;
  const u16* p1 = buf + pstride;
  const u16* p2 = buf + 2 * pstride;
  const u16* p3 = buf + 3 * pstride;
  const u16* p4 = buf + 4 * pstride;
  float x2prev = (s == 0) ? d_init[ch]
                          : bf2f(X2B[(size_t)(s - 1) * NCH + ch]);
  float a1 = 1.f, b1 = 0.f, a2 = 1.f, b2 = 0.f;
  size_t idx = (size_t)(sl * 32) * NCH + ch;
#pragma unroll 4
  for (int tt = 0; tt < SEGLEN; ++tt, idx += NCH) {
    float x1 = bf2f(p0[idx]), x2 = bf2f(p1[idx]), x3 = bf2f(p2[idx]);
    float f1 = bf2f(p3[idx]), f2 = bf2f(p4[idx]);
    a1 *= f1; b1 = f1 * b1 + (1.f - f1) * x1;
    float tmp = x3 * x2prev;
    a2 *= f2; b2 = f2 * b2 + (1.f - f2) * tmp;
    x2prev = x2;
  }
  int o = s * NCH + ch;
  A1[o] = a1; B1[o] = b1; A2[o] = a2; B2[o] = b2;
}

// -------------------------------------------------------------------------
// Pass B: compose the 64 segment maps per channel -> carry-in per segment,
// plus final states (c1_f, c2_f, d_f) directly into out (f32).
__global__ __launch_bounds__(256) void scanB_kernel(
    const float* __restrict__ A1, const float* __restrict__ B1,
    const float* __restrict__ A2, const float* __restrict__ B2,
    const float* __restrict__ c1_init, const float* __restrict__ c2_init,
    const u16* __restrict__ X2B,
    float* __restrict__ C1c, float* __restrict__ C2c, float* __restrict__ out) {
  int ch = blockIdx.x * 256 + threadIdx.x;  // < 8192
  float c1 = c1_init[ch], c2 = c2_init[ch];
#pragma unroll 8
  for (int s = 0; s < SEGS; ++s) {
    int o = s * NCH + ch;
    C1c[o] = c1; C2c[o] = c2;
    c1 = A1[o] * c1 + B1[o];
    c2 = A2[o] * c2 + B2[o];
  }
  out[OFF_C1F + ch] = c1;
  out[OFF_C2F + ch] = c2;
  // d_f = x2 (flipped domain) at t = 2047 = segment-boundary slot 63
  out[OFF_DF + ch] = bf2f(X2B[(size_t)63 * NCH + ch]);
}

// -------------------------------------------------------------------------
// Pass C (per chunk): replay with known carries, write c1s/c2s as f32
// (un-flip dir=1 on store).
__global__ __launch_bounds__(256) void scanC_kernel(
    const u16* __restrict__ buf, const float* __restrict__ d_init,
    const u16* __restrict__ X2B,
    const float* __restrict__ C1c, const float* __restrict__ C2c,
    float* __restrict__ out, int c, int CHT) {
  int bid = blockIdx.x;
  int sl = bid >> 5, chg = bid & 31;
  int ch = chg * 256 + threadIdx.x;
  int s = c * (CHT / 32) + sl;
  size_t pstride = (size_t)CHT * NCH;
  const u16* p0 = buf;
  const u16* p1 = buf + pstride;
  const u16* p2 = buf + 2 * pstride;
  const u16* p3 = buf + 3 * pstride;
  const u16* p4 = buf + 4 * pstride;
  float x2prev = (s == 0) ? d_init[ch]
                          : bf2f(X2B[(size_t)(s - 1) * NCH + ch]);
  float c1 = C1c[s * NCH + ch];
  float c2 = C2c[s * NCH + ch];
  int dir = (ch >> 8) & 1;
  size_t idx = (size_t)(sl * 32) * NCH + ch;
#pragma unroll 4
  for (int tt = 0; tt < SEGLEN; ++tt, idx += NCH) {
    float x1 = bf2f(p0[idx]), x2 = bf2f(p1[idx]), x3 = bf2f(p2[idx]);
    float f1 = bf2f(p3[idx]), f2 = bf2f(p4[idx]);
    c1 = f1 * c1 + (1.f - f1) * x1;
    float tmp = x3 * x2prev;
    c2 = f2 * c2 + (1.f - f2) * tmp;
    x2prev = x2;
    int tfl = s * 32 + tt;
    int t_out = dir ? (SL - 1 - tfl) : tfl;
    size_t oidx = (size_t)t_out * NCH + ch;
    out[oidx] = c1;
    out[OFF_C2S + oidx] = c2;
  }
}

// -------------------------------------------------------------------------
extern "C" void kernel_launch(void* const* d_in, const int* in_sizes, int n_in,
                              void* d_out, int out_size, void* d_ws, size_t ws_size,
                              hipStream_t stream) {
  const float* x    = (const float*)d_in[0];   // (2048,16,256) f32
  const float* W    = (const float*)d_in[1];   // (256,3072) f32
  const float* bias = (const float*)d_in[2];   // (3072,) f32
  const float* c1i  = (const float*)d_in[3];   // (16,512) f32
  const float* c2i  = (const float*)d_in[4];
  const float* di   = (const float*)d_in[5];
  float* out = (float*)d_out;                  // f32 output (ref dtype)

  uint8_t* w8 = (uint8_t*)d_ws;
  u16* Wt  = (u16*)w8;                              // 1,310,720 B
  u16* X2B = (u16*)(w8 + 1310720ull);               // 1,048,576 B
  float* A1  = (float*)(w8 + 2359296ull);           // 6 x 2,097,152 B
  float* B1  = A1 + SEGS * NCH;
  float* A2  = B1 + SEGS * NCH;
  float* B2  = A2 + SEGS * NCH;
  float* C1c = B2 + SEGS * NCH;
  float* C2c = C1c + SEGS * NCH;
  const size_t FIXED = 2359296ull + 6ull * 2097152ull;  // 14,942,208 B
  u16* buf = (u16*)(w8 + FIXED);

  // pick the least chunking that fits ws_size (call-invariant)
  int NCHUNK = 64;
  size_t avail = (ws_size > FIXED) ? (ws_size - FIXED) : 0;
  for (int nc = 1; nc <= 64; nc <<= 1) {
    size_t need = (size_t)5 * (SL / nc) * NCH * 2;
    if (need <= avail) { NCHUNK = nc; break; }
  }
  const int CHT = SL / NCHUNK;

  hipLaunchKernelGGL(repack_kernel, dim3(2560), dim3(256), 0, stream, W, Wt);
  for (int c = 0; c < NCHUNK; ++c) {
    hipLaunchKernelGGL(gemm_kernel, dim3(CHT / 4, 4), dim3(256), 0, stream,
                       x, Wt, bias, buf, X2B, c * CHT, CHT);
    hipLaunchKernelGGL(scanA_kernel, dim3(CHT), dim3(256), 0, stream,
                       buf, di, X2B, A1, B1, A2, B2, c, CHT);
  }
  hipLaunchKernelGGL(scanB_kernel, dim3(32), dim3(256), 0, stream,
                     A1, B1, A2, B2, c1i, c2i, X2B, C1c, C2c, out);
  for (int c = 0; c < NCHUNK; ++c) {
    if (NCHUNK > 1)
      hipLaunchKernelGGL(gemm_kernel, dim3(CHT / 4, 4), dim3(256), 0, stream,
                         x, Wt, bias, buf, X2B, c * CHT, CHT);
    hipLaunchKernelGGL(scanC_kernel, dim3(CHT), dim3(256), 0, stream,
                       buf, di, X2B, C1c, C2c, out, c, CHT);
  }
}